// Round 12
// baseline (366.753 us; speedup 1.0000x reference)
//
#include <hip/hip_runtime.h>
#include <math.h>

#define T_ 16
#define B_ 512
#define N_ 8192
#define G_ 39
#define ENC_ 128
#define TH_ 64
#define MROWS 8704          // B_ + N_
#define GATE 512            // 4*ENC_
#define KCAT 192            // TH_ + ENC_
#define SCALE_ 0.08838834764831845f
#define LNEPS 1e-5f
#define NBLK 136            // MROWS/64

typedef short bf16x8 __attribute__((ext_vector_type(8)));
typedef float f32x4  __attribute__((ext_vector_type(4)));

__device__ __forceinline__ float sigm(float x){ return 1.0f/(1.0f+expf(-x)); }
__device__ __forceinline__ float rcpf(float x){ return __builtin_amdgcn_rcpf(x); }
__device__ __forceinline__ float sigm_f(float x){ return rcpf(1.0f + __expf(-x)); }
__device__ __forceinline__ float tanh_f(float x){ return 1.0f - 2.0f*rcpf(__expf(2.0f*x) + 1.0f); }
__device__ __forceinline__ unsigned short f2bf(float f){
  unsigned int u = __float_as_uint(f);
  unsigned int r = u + 0x7FFFu + ((u>>16)&1u);
  return (unsigned short)(r>>16);
}
__device__ __forceinline__ float bf2f(unsigned short h){
  return __uint_as_float(((unsigned int)h)<<16);
}

// ================= prep: convert weights to bf16, build fused/block-diag mats ========
__global__ __launch_bounds__(256) void k_prep(
    const float* __restrict__ Wih, const float* __restrict__ Whh,
    const float* __restrict__ bih, const float* __restrict__ bhh,
    const float* __restrict__ Wk,  const float* __restrict__ Wv,
    const float* __restrict__ Wq,
    const float* __restrict__ Wqt, const float* __restrict__ bqt,
    const float* __restrict__ Wkt, const float* __restrict__ bkt,
    const float* __restrict__ Wvt, const float* __restrict__ bvt,
    const float* __restrict__ Wg1a, const float* __restrict__ bg1a,
    const float* __restrict__ Wg1g, const float* __restrict__ bg1g,
    const float* __restrict__ Wg2a, const float* __restrict__ bg2a,
    const float* __restrict__ Wg2g, const float* __restrict__ bg2g,
    unsigned short* __restrict__ WcatB, float* __restrict__ biasg,
    unsigned short* __restrict__ WqB,
    unsigned short* __restrict__ WkD,  unsigned short* __restrict__ WvD,
    float* __restrict__ zero512,
    unsigned short* __restrict__ WqktB, float* __restrict__ bqkt,
    unsigned short* __restrict__ Wg1B,  float* __restrict__ bg1,
    unsigned short* __restrict__ Wg2B,  float* __restrict__ bg2)
{
  int i = blockIdx.x*256 + threadIdx.x;
  if (i < GATE*KCAT) {
    int n = i / KCAT, k = i % KCAT;
    WcatB[i] = f2bf((k < TH_) ? Wih[n*TH_ + k] : Whh[n*ENC_ + (k - TH_)]);
  }
  if (i < GATE) biasg[i] = bih[i] + bhh[i];
  if (i < ENC_*ENC_) WqB[i] = f2bf(Wq[i]);
  if (i < 512*128) {
    int r = i >> 7, dc = i & 127;
    int h = r >> 7, e = r & 127;
    WkD[i] = ((dc >> 5) == h) ? f2bf(Wk[dc*128 + e]) : (unsigned short)0;
  }
  if (i < 128*512) {
    int r = i >> 9, kk = i & 511;
    int hp = kk >> 7, e = kk & 127;
    WvD[i] = (hp == (r >> 5)) ? f2bf(Wv[r*128 + e]) : (unsigned short)0;
  }
  if (i < 512) zero512[i] = 0.0f;
  if (i < 2*ENC_*ENC_) {
    int n = i >> 7, k = i & 127;
    Wg1B[i] = f2bf((n < ENC_) ? Wg1a[n*ENC_ + k] : Wg1g[(n-ENC_)*ENC_ + k]);
    Wg2B[i] = f2bf((n < ENC_) ? Wg2a[n*ENC_ + k] : Wg2g[(n-ENC_)*ENC_ + k]);
  }
  if (i < 2*ENC_) {
    bg1[i] = (i < ENC_) ? bg1a[i] : bg1g[i-ENC_];
    bg2[i] = (i < ENC_) ? bg2a[i] : bg2g[i-ENC_];
  }
  if (i < 3*ENC_*ENC_) {
    int n = i >> 7, k = i & 127;
    float w = (n < ENC_) ? Wqt[n*ENC_ + k] : (n < 2*ENC_) ? Wkt[(n-ENC_)*ENC_ + k]
                                                          : Wvt[(n-2*ENC_)*ENC_ + k];
    WqktB[i] = f2bf(w);
  }
  if (i < 3*ENC_) bqkt[i] = (i < ENC_) ? bqt[i] : (i < 2*ENC_) ? bkt[i-ENC_] : bvt[i-2*ENC_];
}

// ================= mask width detect / count / fill (proven) =========================
__device__ __forceinline__ int cellval(const unsigned char* m, long cell, int w) {
  long byte = cell * 128L * w;
  if (w == 1) return m[byte] != 0;
  if (w == 2) return *(const unsigned short*)(m + byte) != 0;
  if (w == 4) return *(const unsigned int*)(m + byte) != 0;
  return *(const unsigned long long*)(m + byte) != 0ULL;
}
__device__ __forceinline__ int cellconsist(const unsigned char* m, long cell, int w) {
  long byte = cell * 128L * w;
  if (w == 1) { unsigned char v = m[byte];
    for (int j = 1; j < 8; ++j) if (m[byte + j] != v) return 0; return 1; }
  if (w == 2) { unsigned short v = *(const unsigned short*)(m + byte);
    for (int j = 1; j < 8; ++j) if (*(const unsigned short*)(m + byte + 2L*j) != v) return 0; return 1; }
  if (w == 4) { unsigned int v = *(const unsigned int*)(m + byte);
    for (int j = 1; j < 8; ++j) if (*(const unsigned int*)(m + byte + 4L*j) != v) return 0; return 1; }
  unsigned long long v = *(const unsigned long long*)(m + byte);
  for (int j = 1; j < 8; ++j) if (*(const unsigned long long*)(m + byte + 8L*j) != v) return 0; return 1;
}

__global__ void k_detect(const unsigned char* __restrict__ mask, int* __restrict__ wsel)
{
  __shared__ int bad;
  int tid = threadIdx.x;
  int chosen = 0;
  for (int w = 1; w <= 8 && !chosen; w <<= 1) {
    if (tid == 0) bad = 0;
    __syncthreads();
    int ok = 1;
    for (int c = tid; c < 512; c += 256) ok &= cellconsist(mask, c, w);
    if (!ok) bad = 1;
    __syncthreads();
    if (!bad) chosen = w;
    __syncthreads();
  }
  if (tid == 0) *wsel = chosen ? chosen : 1;
}

__global__ void k_count(const unsigned char* __restrict__ mask,
                        const int* __restrict__ wsel, int* __restrict__ bcnt)
{
  __shared__ int sc[256];
  int tid = threadIdx.x;
  long cell = (long)blockIdx.x*256 + tid;
  sc[tid] = cellval(mask, cell, *wsel);
  __syncthreads();
  for (int off = 128; off; off >>= 1) {
    if (tid < off) sc[tid] += sc[tid + off];
    __syncthreads();
  }
  if (tid == 0) bcnt[blockIdx.x] = sc[0];
}

__global__ void k_fill(const unsigned char* __restrict__ mask,
                       const int* __restrict__ wsel, const int* __restrict__ bcnt,
                       int* __restrict__ nidx)
{
  __shared__ int sc[256];
  int tid = threadIdx.x, blk = blockIdx.x;
  long cell = (long)blk*256 + tid;
  int on = cellval(mask, cell, *wsel);
  sc[tid] = on;
  __syncthreads();
  for (int off = 1; off < 256; off <<= 1) {
    int v = (tid >= off) ? sc[tid - off] : 0;
    __syncthreads();
    sc[tid] += v;
    __syncthreads();
  }
  int base = 0;
  for (int i = 0; i < blk; ++i) base += bcnt[i];
  nidx[cell] = on ? (base + sc[tid] - 1) : -1;
}

// ================= encode ALL t: elu(in5 @ W1^T + b1) -> XencB[t][m][64] bf16 =========
__global__ __launch_bounds__(256) void k_encode_all(
    const float* __restrict__ hist, const float* __restrict__ cls, const float* __restrict__ va,
    const float* __restrict__ nbrs, const float* __restrict__ nbrscls, const float* __restrict__ nbrsva,
    const float* __restrict__ W1, const float* __restrict__ b1,
    unsigned short* __restrict__ XencB)
{
  int i = blockIdx.x*256 + threadIdx.x;      // over MROWS*64
  int t = blockIdx.y;
  int o = i & 63, m = i >> 6;
  float in0, in1, in2, in3, in4;
  if (m < B_) {
    int r = t*B_ + m;
    in0 = hist[r*2]; in1 = hist[r*2+1]; in2 = cls[r]; in3 = va[r*2]; in4 = va[r*2+1];
  } else {
    int r = t*N_ + (m - B_);
    in0 = nbrs[r*2]; in1 = nbrs[r*2+1]; in2 = nbrscls[r]; in3 = nbrsva[r*2]; in4 = nbrsva[r*2+1];
  }
  const float* w = W1 + o*5;
  float s = b1[o] + in0*w[0] + in1*w[1] + in2*w[2] + in3*w[3] + in4*w[4];
  XencB[((long)t*MROWS + m)*64 + o] = f2bf((s > 0.0f) ? s : expm1f(s));
}

// ================= kernel A: LSTM; pinned weights, prefetch, relaxed barrier =========
struct AP {
  const unsigned short *Xenc, *Wcat, *Wq;
  const float *biasg, *bq;
  float *hh;                 // (B,T,128) f32
  unsigned short *qB;        // (T,B,128) bf16
  unsigned short *HnB;       // (T,N,128) bf16
};

// 136 blocks x 64 rows; 512 threads = 8 waves; wave w owns gate-channels w*16..+16
// (all 4 gates). ALL gate weights pinned in regs; Xenc prefetched one t ahead;
// barrier waits lgkmcnt only (global stores drain lazily across iterations).
__global__ __launch_bounds__(512, 1) void k_lstm(AP p)
{
  __shared__ unsigned short Hl[2*64*128];    // 32 KB, double-buffered, XOR-swizzled

  const int tid = threadIdx.x;
  const int w = tid >> 6, l = tid & 63;
  const int lr = l & 15, lk = (l >> 4) * 8, lq = (l >> 4) * 4;
  const int bi = blockIdx.x, bm = bi * 64;
  const bool ish = (bi < 8);

  // gate weights pinned: X-part (2 ks) + H-part (4 ks), 4 gates
  bf16x8 wgx[4][2], wgh[4][4];
  #pragma unroll
  for (int g = 0; g < 4; ++g) {
    #pragma unroll
    for (int ks = 0; ks < 2; ++ks)
      wgx[g][ks] = *(const bf16x8*)(p.Wcat + (long)(g*128 + w*16 + lr)*KCAT + ks*32 + lk);
    #pragma unroll
    for (int ks = 0; ks < 4; ++ks)
      wgh[g][ks] = *(const bf16x8*)(p.Wcat + (long)(g*128 + w*16 + lr)*KCAT + 64 + ks*32 + lk);
  }

  const int ch = w*16 + lr;
  float bgv[4];
  #pragma unroll
  for (int g = 0; g < 4; ++g) bgv[g] = p.biasg[g*128 + ch];
  const float bqv = ish ? p.bq[ch] : 0.0f;

  for (int i = tid; i < 64*128; i += 512) Hl[i] = 0;   // H(0) buffer 0
  float creg[4][4];
  #pragma unroll
  for (int mi = 0; mi < 4; ++mi)
    #pragma unroll
    for (int q = 0; q < 4; ++q) creg[mi][q] = 0.0f;

  // prefetch t=0 Xenc A-frags
  bf16x8 axc[2][4];
  #pragma unroll
  for (int ks = 0; ks < 2; ++ks)
    #pragma unroll
    for (int mi = 0; mi < 4; ++mi)
      axc[ks][mi] = *(const bf16x8*)(p.Xenc + ((long)0*MROWS + bm + mi*16 + lr)*64 + ks*32 + lk);

  __syncthreads();

  int cur = 0;
  for (int t = 0; t < T_; ++t) {
    // ---- gate GEMM: acc init with bias; X-part from prefetched regs ----
    f32x4 acc[4][4];
    #pragma unroll
    for (int g = 0; g < 4; ++g)
      #pragma unroll
      for (int mi = 0; mi < 4; ++mi) {
        f32x4 v = { bgv[g], bgv[g], bgv[g], bgv[g] };
        acc[g][mi] = v;
      }
    #pragma unroll
    for (int ks = 0; ks < 2; ++ks)
      #pragma unroll
      for (int g = 0; g < 4; ++g)
        #pragma unroll
        for (int mi = 0; mi < 4; ++mi)
          acc[g][mi] = __builtin_amdgcn_mfma_f32_16x16x32_bf16(axc[ks][mi], wgx[g][ks], acc[g][mi], 0, 0, 0);
    // ---- prefetch next t's Xenc (regs dead after the MFMAs above) ----
    if (t + 1 < T_) {
      #pragma unroll
      for (int ks = 0; ks < 2; ++ks)
        #pragma unroll
        for (int mi = 0; mi < 4; ++mi)
          axc[ks][mi] = *(const bf16x8*)(p.Xenc + ((long)(t+1)*MROWS + bm + mi*16 + lr)*64 + ks*32 + lk);
    }
    // ---- H-part from Hl[cur] ----
    #pragma unroll
    for (int ks = 0; ks < 4; ++ks) {
      bf16x8 a[4];
      #pragma unroll
      for (int mi = 0; mi < 4; ++mi) {
        int row = mi*16 + lr;
        int col = (ks*32 + lk) ^ ((row & 7) << 3);
        a[mi] = *(const bf16x8*)(Hl + cur*8192 + row*128 + col);
      }
      #pragma unroll
      for (int g = 0; g < 4; ++g)
        #pragma unroll
        for (int mi = 0; mi < 4; ++mi)
          acc[g][mi] = __builtin_amdgcn_mfma_f32_16x16x32_bf16(a[mi], wgh[g][ks], acc[g][mi], 0, 0, 0);
    }
    // ---- lane-local cell update (c in registers) ----
    int nxt = cur ^ 1;
    #pragma unroll
    for (int mi = 0; mi < 4; ++mi)
      #pragma unroll
      for (int q = 0; q < 4; ++q) {
        int row = mi*16 + lq + q;
        float gi = acc[0][mi][q];
        float gf = acc[1][mi][q];
        float gg = acc[2][mi][q];
        float go = acc[3][mi][q];
        float cc = sigm_f(gf)*creg[mi][q] + sigm_f(gi)*tanh_f(gg);
        creg[mi][q] = cc;
        float hv = sigm_f(go)*tanh_f(cc);
        Hl[nxt*8192 + row*128 + (ch ^ ((row & 7) << 3))] = f2bf(hv);
        if (ish) p.hh[((long)(bm + row)*T_ + t)*128 + ch] = hv;
      }
    // ---- relaxed barrier: LDS visibility only; global stores stay in flight ----
    __builtin_amdgcn_sched_barrier(0);
    asm volatile("s_waitcnt lgkmcnt(0)" ::: "memory");
    __builtin_amdgcn_s_barrier();
    __builtin_amdgcn_sched_barrier(0);
    cur = nxt;
    if (ish) {
      // ---- q projection from new H ----
      f32x4 a2[4];
      #pragma unroll
      for (int mi = 0; mi < 4; ++mi) {
        f32x4 v = { bqv, bqv, bqv, bqv };
        a2[mi] = v;
      }
      #pragma unroll
      for (int ks = 0; ks < 4; ++ks) {
        bf16x8 b = *(const bf16x8*)(p.Wq + (long)(w*16 + lr)*128 + ks*32 + lk);
        #pragma unroll
        for (int mi = 0; mi < 4; ++mi) {
          int row = mi*16 + lr;
          int col = (ks*32 + lk) ^ ((row & 7) << 3);
          bf16x8 a = *(const bf16x8*)(Hl + cur*8192 + row*128 + col);
          a2[mi] = __builtin_amdgcn_mfma_f32_16x16x32_bf16(a, b, a2[mi], 0, 0, 0);
        }
      }
      #pragma unroll
      for (int mi = 0; mi < 4; ++mi)
        #pragma unroll
        for (int q = 0; q < 4; ++q)
          p.qB[((long)t*B_ + bm + mi*16 + lq + q)*128 + ch] = f2bf(a2[mi][q]);
    } else {
      // ---- staged, coalesced copy of new H -> HnB: 64 rows x 16 chunks of 16B ----
      for (int e = tid; e < 64*16; e += 512) {
        int r = e >> 4, j = e & 15;
        int src = cur*8192 + r*128 + ((j*8) ^ ((r & 7) << 3));
        *(bf16x8*)(p.HnB + ((long)t*N_ + (bm - B_) + r)*128 + j*8) =
            *(const bf16x8*)(Hl + src);
      }
    }
  }
}

// ================= kernel B: spatial attention via qW/hbar (no kv) ===================
__global__ __launch_bounds__(128) void k_attn2(
    const unsigned short* __restrict__ qB,    // (T,B,128)
    const unsigned short* __restrict__ qWB,   // (T*B, 512)
    const unsigned short* __restrict__ HnB,   // (T,N,128)
    const float* __restrict__ bk,
    const int* __restrict__ nidx,
    unsigned short* __restrict__ hbarB)       // (B*T, 512)
{
  __shared__ int sn[G_];
  __shared__ unsigned short hL[G_*128];
  __shared__ float sgh[G_][4];
  int blk = blockIdx.x;
  int b = blk >> 4, t = blk & 15;
  int tid = threadIdx.x;
  int h = tid >> 5, d = tid & 31;
  if (tid < G_) sn[tid] = nidx[b*G_ + tid];
  __syncthreads();
  for (int g = 0; g < G_; ++g) {
    int ni = sn[g];
    if (ni >= 0) hL[g*128 + tid] = HnB[((long)t*N_ + ni)*128 + tid];
  }
  float qel = bf2f(qB[((long)t*B_ + b)*128 + tid]);
  float qbk = qel * bk[tid];
  #pragma unroll
  for (int off = 16; off; off >>= 1) qbk += __shfl_xor(qbk, off);
  float qw[4];
  #pragma unroll
  for (int j = 0; j < 4; ++j)
    qw[j] = bf2f(qWB[((long)t*B_ + b)*512 + h*128 + d + j*32]);
  __syncthreads();
  for (int g = 0; g < G_; ++g) {
    float s;
    if (sn[g] >= 0) {
      float part = 0.0f;
      #pragma unroll
      for (int j = 0; j < 4; ++j) part += bf2f(hL[g*128 + d + j*32]) * qw[j];
      #pragma unroll
      for (int off = 16; off; off >>= 1) part += __shfl_xor(part, off);
      s = (part + qbk) * SCALE_;
    } else {
      s = qbk * SCALE_;
    }
    if (d == 0) sgh[g][h] = s;
  }
  float mx = -1e30f;
  for (int g = 0; g < G_; ++g) mx = fmaxf(mx, sgh[g][h]);
  float den = 0.0f;
  float hb[4] = {0.0f, 0.0f, 0.0f, 0.0f};
  for (int g = 0; g < G_; ++g) {
    float e = expf(sgh[g][h] - mx);
    den += e;
    if (sn[g] >= 0) {
      #pragma unroll
      for (int j = 0; j < 4; ++j) hb[j] += e * bf2f(hL[g*128 + d + j*32]);
    }
  }
  float inv = 1.0f / den;
  #pragma unroll
  for (int j = 0; j < 4; ++j)
    hbarB[((long)b*T_ + t)*512 + h*128 + d + j*32] = f2bf(hb[j] * inv);
}

// ================= bf16 MFMA GEMM: C f32 out =========================================
__global__ __launch_bounds__(256) void k_gemm_bf16(
    const unsigned short* __restrict__ A, int lda,
    const unsigned short* __restrict__ W, int ldw,
    const float* __restrict__ bias,
    float* __restrict__ C, int ldc, int K)
{
  int tid = threadIdx.x;
  int w = tid >> 6, l = tid & 63;
  int lr = l & 15, lk = (l >> 4) * 8, lq = (l >> 4) * 4;
  int bm = blockIdx.x * 64;
  int bn = blockIdx.y * 128 + w * 32;
  f32x4 acc[4][2] = {};
  for (int k0 = 0; k0 < K; k0 += 32) {
    bf16x8 a[4], b[2];
    #pragma unroll
    for (int mi = 0; mi < 4; ++mi)
      a[mi] = *(const bf16x8*)(A + (long)(bm + mi*16 + lr)*lda + k0 + lk);
    #pragma unroll
    for (int ni = 0; ni < 2; ++ni)
      b[ni] = *(const bf16x8*)(W + (long)(bn + ni*16 + lr)*ldw + k0 + lk);
    #pragma unroll
    for (int mi = 0; mi < 4; ++mi)
      #pragma unroll
      for (int ni = 0; ni < 2; ++ni)
        acc[mi][ni] = __builtin_amdgcn_mfma_f32_16x16x32_bf16(a[mi], b[ni], acc[mi][ni], 0, 0, 0);
  }
  #pragma unroll
  for (int mi = 0; mi < 4; ++mi)
    #pragma unroll
    for (int ni = 0; ni < 2; ++ni) {
      int col = bn + ni*16 + lr;
      float bb = bias[col];
      #pragma unroll
      for (int q = 0; q < 4; ++q)
        C[(long)(bm + mi*16 + lq + q)*ldc + col] = acc[mi][ni][q] + bb;
    }
}

// same but bf16 output
__global__ __launch_bounds__(256) void k_gemm_bf16o(
    const unsigned short* __restrict__ A, int lda,
    const unsigned short* __restrict__ W, int ldw,
    const float* __restrict__ bias,
    unsigned short* __restrict__ C, int ldc, int K)
{
  int tid = threadIdx.x;
  int w = tid >> 6, l = tid & 63;
  int lr = l & 15, lk = (l >> 4) * 8, lq = (l >> 4) * 4;
  int bm = blockIdx.x * 64;
  int bn = blockIdx.y * 128 + w * 32;
  f32x4 acc[4][2] = {};
  for (int k0 = 0; k0 < K; k0 += 32) {
    bf16x8 a[4], b[2];
    #pragma unroll
    for (int mi = 0; mi < 4; ++mi)
      a[mi] = *(const bf16x8*)(A + (long)(bm + mi*16 + lr)*lda + k0 + lk);
    #pragma unroll
    for (int ni = 0; ni < 2; ++ni)
      b[ni] = *(const bf16x8*)(W + (long)(bn + ni*16 + lr)*ldw + k0 + lk);
    #pragma unroll
    for (int mi = 0; mi < 4; ++mi)
      #pragma unroll
      for (int ni = 0; ni < 2; ++ni)
        acc[mi][ni] = __builtin_amdgcn_mfma_f32_16x16x32_bf16(a[mi], b[ni], acc[mi][ni], 0, 0, 0);
  }
  #pragma unroll
  for (int mi = 0; mi < 4; ++mi)
    #pragma unroll
    for (int ni = 0; ni < 2; ++ni) {
      int col = bn + ni*16 + lr;
      float bb = bias[col];
      #pragma unroll
      for (int q = 0; q < 4; ++q)
        C[(long)(bm + mi*16 + lq + q)*ldc + col] = f2bf(acc[mi][ni][q] + bb);
    }
}

// ================= fused glu + residual add + layernorm ==============================
__global__ __launch_bounds__(256) void k_glu_addln(
    const float* __restrict__ t12, const float* __restrict__ res,
    const float* __restrict__ lg, const float* __restrict__ lb,
    float* __restrict__ sum_out, unsigned short* __restrict__ ln_bf16,
    float* __restrict__ ln_f32)
{
  int gtid = blockIdx.x*256 + threadIdx.x;
  int r = gtid >> 6;
  int l = threadIdx.x & 63;
  if (r >= B_*T_) return;
  long b4 = (long)r*256, b2 = (long)r*128;
  float xA = res[b2 + l]      + t12[b4 + l]      * sigm(t12[b4 + 128 + l]);
  float xB = res[b2 + 64 + l] + t12[b4 + 64 + l] * sigm(t12[b4 + 192 + l]);
  if (sum_out) { sum_out[b2 + l] = xA; sum_out[b2 + 64 + l] = xB; }
  float s = xA + xB, s2 = xA*xA + xB*xB;
  #pragma unroll
  for (int off = 32; off; off >>= 1) { s += __shfl_xor(s, off); s2 += __shfl_xor(s2, off); }
  float mean = s * (1.0f/128.0f);
  float var  = s2 * (1.0f/128.0f) - mean*mean;
  float inv  = rsqrtf(var + LNEPS);
  float oA = (xA - mean)*inv*lg[l]      + lb[l];
  float oB = (xB - mean)*inv*lg[64 + l] + lb[64 + l];
  if (ln_bf16) { ln_bf16[b2 + l] = f2bf(oA); ln_bf16[b2 + 64 + l] = f2bf(oB); }
  if (ln_f32)  { ln_f32[b2 + l] = oA;        ln_f32[b2 + 64 + l] = oB; }
}

// ================= temporal attention (bf16 qkt input) ===============================
__global__ __launch_bounds__(128) void k_attn_t(
    const unsigned short* __restrict__ qkt, unsigned short* __restrict__ out)
{
  int b = blockIdx.x, tid = threadIdx.x;
  __shared__ float sq[16][128], sk[16][128], sv[16][128];
  __shared__ float sc[16][4][16];
  for (int i = tid; i < T_*ENC_; i += 128) {
    int tt = i >> 7, j = i & 127;
    long a = ((long)b*T_ + tt)*384;
    sq[tt][j] = bf2f(qkt[a + j]);
    sk[tt][j] = bf2f(qkt[a + 128 + j]);
    sv[tt][j] = bf2f(qkt[a + 256 + j]);
  }
  __syncthreads();
  for (int e = tid; e < 1024; e += 128) {
    int t = e >> 6, s = (e >> 2) & 15, h2 = e & 3;
    float pp = 0.0f;
    #pragma unroll
    for (int d2 = 0; d2 < 32; ++d2) pp += sq[t][h2*32 + d2] * sk[s][h2*32 + d2];
    sc[t][h2][s] = pp * SCALE_;
  }
  __syncthreads();
  if (tid < 64) {
    int t = tid >> 2, h2 = tid & 3;
    float mx = -1e30f;
    for (int s = 0; s < 16; ++s) mx = fmaxf(mx, sc[t][h2][s]);
    float sum = 0.0f;
    for (int s = 0; s < 16; ++s) { float e2 = expf(sc[t][h2][s] - mx); sc[t][h2][s] = e2; sum += e2; }
    float inv = 1.0f / sum;
    for (int s = 0; s < 16; ++s) sc[t][h2][s] *= inv;
  }
  __syncthreads();
  int h2 = tid >> 5, d2 = tid & 31;
  for (int t = 0; t < 16; ++t) {
    float acc = 0.0f;
    for (int s = 0; s < 16; ++s) acc += sc[t][h2][s] * sv[s][h2*32 + d2];
    out[((long)b*T_ + t)*128 + tid] = f2bf(acc);
  }
}

extern "C" void kernel_launch(void* const* d_in, const int* in_sizes, int n_in,
                              void* d_out, int out_size, void* d_ws, size_t ws_size,
                              hipStream_t stream)
{
  const float* hist    = (const float*)d_in[0];
  const float* nbrs    = (const float*)d_in[1];
  const float* va      = (const float*)d_in[2];
  const float* nbrsva  = (const float*)d_in[3];
  const float* cls     = (const float*)d_in[6];
  const float* nbrscls = (const float*)d_in[7];
  const unsigned char* mask = (const unsigned char*)d_in[8];
  const float* W1  = (const float*)d_in[9];
  const float* b1  = (const float*)d_in[10];
  const float* Wih = (const float*)d_in[11];
  const float* Whh = (const float*)d_in[12];
  const float* bih = (const float*)d_in[13];
  const float* bhh = (const float*)d_in[14];
  const float* Wq  = (const float*)d_in[15];
  const float* bq  = (const float*)d_in[16];
  const float* Wk  = (const float*)d_in[17];
  const float* bk  = (const float*)d_in[18];
  const float* Wv  = (const float*)d_in[19];
  const float* bv  = (const float*)d_in[20];
  const float* Wg1a = (const float*)d_in[21];
  const float* bg1a = (const float*)d_in[22];
  const float* Wg1g = (const float*)d_in[23];
  const float* bg1g = (const float*)d_in[24];
  const float* Wqt = (const float*)d_in[25];
  const float* bqt = (const float*)d_in[26];
  const float* Wkt = (const float*)d_in[27];
  const float* bkt = (const float*)d_in[28];
  const float* Wvt = (const float*)d_in[29];
  const float* bvt = (const float*)d_in[30];
  const float* Wg2a = (const float*)d_in[31];
  const float* bg2a = (const float*)d_in[32];
  const float* Wg2g = (const float*)d_in[33];
  const float* bg2g = (const float*)d_in[34];
  const float* ln_g = (const float*)d_in[35];
  const float* ln_b = (const float*)d_in[36];

  char* base = (char*)d_ws;
  size_t off = 0;
  auto alloc = [&](size_t bytes) { char* r = base + off; off = (off + bytes + 255) & ~(size_t)255; return r; };
  unsigned short* WcatB = (unsigned short*)alloc(GATE*KCAT*2);
  float*          biasg = (float*)alloc(GATE*4);
  unsigned short* WqB   = (unsigned short*)alloc(ENC_*ENC_*2);
  unsigned short* WkD   = (unsigned short*)alloc(512*128*2);
  unsigned short* WvD   = (unsigned short*)alloc(128*512*2);
  float*          zero512 = (float*)alloc(512*4);
  unsigned short* WqktB = (unsigned short*)alloc(3*ENC_*ENC_*2);
  float*          bqkt  = (float*)alloc(3*ENC_*4);
  unsigned short* Wg1B  = (unsigned short*)alloc(2*ENC_*ENC_*2);
  float*          bg1   = (float*)alloc(2*ENC_*4);
  unsigned short* Wg2B  = (unsigned short*)alloc(2*ENC_*ENC_*2);
  float*          bg2   = (float*)alloc(2*ENC_*4);
  unsigned short* XencB = (unsigned short*)alloc((size_t)T_*MROWS*64*2);
  float*          hh    = (float*)alloc((size_t)B_*T_*ENC_*4);
  unsigned short* qB    = (unsigned short*)alloc((size_t)T_*B_*ENC_*2);
  unsigned short* HnB   = (unsigned short*)alloc((size_t)T_*N_*ENC_*2);
  unsigned short* qWB   = (unsigned short*)alloc((size_t)T_*B_*512*2);
  unsigned short* hbarB = (unsigned short*)alloc((size_t)B_*T_*512*2);
  unsigned short* spaB  = (unsigned short*)alloc((size_t)B_*T_*ENC_*2);
  float*          t12   = (float*)alloc((size_t)B_*T_*2*ENC_*4);
  float*          S1    = (float*)alloc((size_t)B_*T_*ENC_*4);
  unsigned short* valsB = (unsigned short*)alloc((size_t)B_*T_*ENC_*2);
  unsigned short* qktB  = (unsigned short*)alloc((size_t)B_*T_*3*ENC_*2);
  unsigned short* atoB  = (unsigned short*)alloc((size_t)B_*T_*ENC_*2);
  int*            nidx  = (int*)alloc((size_t)B_*G_*4);
  int*            bcnt  = (int*)alloc(78*4);
  int*            wsel  = (int*)alloc(4);

  const int ROWS = B_*T_;                    // 8192

  k_prep<<<384, 256, 0, stream>>>(
      Wih, Whh, bih, bhh, Wk, Wv, Wq,
      Wqt, bqt, Wkt, bkt, Wvt, bvt,
      Wg1a, bg1a, Wg1g, bg1g, Wg2a, bg2a, Wg2g, bg2g,
      WcatB, biasg, WqB, WkD, WvD, zero512, WqktB, bqkt, Wg1B, bg1, Wg2B, bg2);
  k_detect<<<1, 256, 0, stream>>>(mask, wsel);
  k_count<<<78, 256, 0, stream>>>(mask, wsel, bcnt);
  k_fill<<<78, 256, 0, stream>>>(mask, wsel, bcnt, nidx);
  k_encode_all<<<dim3(MROWS*64/256, T_), 256, 0, stream>>>(
      hist, cls, va, nbrs, nbrscls, nbrsva, W1, b1, XencB);

  AP ap;
  ap.Xenc = XencB; ap.Wcat = WcatB; ap.Wq = WqB;
  ap.biasg = biasg; ap.bq = bq;
  ap.hh = hh; ap.qB = qB; ap.HnB = HnB;
  k_lstm<<<NBLK, 512, 0, stream>>>(ap);

  // qW = q @ WkD^T  (M=8192, N=512, K=128)
  k_gemm_bf16o<<<dim3(ROWS/64, 4), 256, 0, stream>>>(qB, 128, WkD, 128, zero512, qWB, 512, 128);
  // spatial attention -> hbar
  k_attn2<<<ROWS, 128, 0, stream>>>(qB, qWB, HnB, bk, nidx, hbarB);
  // spa = hbar @ WvD^T + bv  (M=8192, N=128, K=512)
  k_gemm_bf16o<<<dim3(ROWS/64, 1), 256, 0, stream>>>(hbarB, 512, WvD, 512, bv, spaB, 128, 512);

  // tail
  k_gemm_bf16<<<dim3(ROWS/64, 2), 256, 0, stream>>>(spaB, 128, Wg1B, 128, bg1, t12, 256, 128);
  k_glu_addln<<<(ROWS*64)/256, 256, 0, stream>>>(t12, hh, ln_g, ln_b, S1, valsB, nullptr);
  k_gemm_bf16o<<<dim3(ROWS/64, 3), 256, 0, stream>>>(valsB, 128, WqktB, 128, bqkt, qktB, 384, 128);
  k_attn_t<<<B_, 128, 0, stream>>>(qktB, atoB);
  k_gemm_bf16<<<dim3(ROWS/64, 2), 256, 0, stream>>>(atoB, 128, Wg2B, 128, bg2, t12, 256, 128);
  k_glu_addln<<<(ROWS*64)/256, 256, 0, stream>>>(t12, S1, ln_g, ln_b, nullptr, nullptr, (float*)d_out);
}